// Round 11
// baseline (328.494 us; speedup 1.0000x reference)
//
#include <hip/hip_runtime.h>

// Problem constants (match reference)
#define NN 100000
#define TT 128
#define EE 1600000
#define KK 9
#define ZROW NN                   // dedicated all-zero row for padded gather lanes

// Binned CSR build: 256-node buckets (BSH=8 -> 391 buckets)
#define BSH 8
#define BMASK 255
#define NBUCK 391                 // ceil(100000/256)
#define BCAP 5120                 // avg 4092/bucket, sigma~64 -> 16 sigma headroom
#define EPB 16384                 // edges per bin block (16/thread; short gcursor chains)
#define BINB 98                   // ceil(EE/EPB)
#define CVTB 3125                 // NN*TT/4 / 1024

typedef _Float16 f16;
typedef __attribute__((ext_vector_type(2))) _Float16 f16x2;
typedef __attribute__((ext_vector_type(4))) _Float16 f16x4;
typedef __attribute__((ext_vector_type(8))) _Float16 f16x8;

union HU8 { f16x8 h; int4 i; };

// ---------- fused: bin edges (blocks 0..BINB) + x fp32->fp16 + zero-row init ----------
// Packed edge: (dlocal << 20) | src   (src < 2^17, dlocal < 2^8)
// Two-pass rank assignment: pass1 LDS hist, gcursor base, pass2 re-read ei (L2-hot)
// and place via LDS cursor. No per-thread val/rank arrays -> low VGPR at 1024 thr.
__global__ __launch_bounds__(1024)
void bin_cvt_kernel(const int* __restrict__ ei, int* __restrict__ gcursor,
                    unsigned int* __restrict__ binned,
                    const float4* __restrict__ x, f16x4* __restrict__ x16,
                    int* __restrict__ zx, int* __restrict__ zyA, int* __restrict__ zyB) {
    __shared__ int hist[NBUCK];
    __shared__ int cur[NBUCK];
    int tid = threadIdx.x;

    if (blockIdx.x >= BINB + CVTB) {          // one block: zero-rows of x16/yA/yB
        int k = tid;                          // 64 dwords each
        if (k >= 0 && k < 64)         zx[k]        = 0;
        else if (k >= 64 && k < 128)  zyA[k - 64]  = 0;
        else if (k >= 128 && k < 192) zyB[k - 128] = 0;
        return;
    }
    if (blockIdx.x >= BINB) {
        // cvt part: one float4 per thread over N*T/4 (exactly CVTB*1024 elements)
        int i = (blockIdx.x - BINB) * 1024 + tid;
        float4 v = x[i];
        f16x4 o;
        o.x = (f16)v.x; o.y = (f16)v.y; o.z = (f16)v.z; o.w = (f16)v.w;
        x16[i] = o;
        return;
    }

    if (tid < NBUCK) hist[tid] = 0;
    __syncthreads();
    int base = blockIdx.x * EPB;
#pragma unroll
    for (int k = 0; k < 16; k++) {            // pass 1: count
        int e = base + k * 1024 + tid;
        if (e < EE) atomicAdd(&hist[ei[EE + e] >> BSH], 1);
    }
    __syncthreads();
    if (tid < NBUCK) cur[tid] = hist[tid] ? atomicAdd(&gcursor[tid], hist[tid]) : 0;
    __syncthreads();
#pragma unroll
    for (int k = 0; k < 16; k++) {            // pass 2: place (ei slice is L2-hot)
        int e = base + k * 1024 + tid;
        if (e < EE) {
            int s = ei[e];
            int d = ei[EE + e];
            int bkt = d >> BSH;
            int r = atomicAdd(&cur[bkt], 1);
            binned[(size_t)bkt * BCAP + r] =
                ((unsigned int)(d & BMASK) << 20) | (unsigned int)s;
        }
    }
}

// ---------- per-bucket (256 nodes): wave-shfl scans (~8 barriers vs ~40) ----------
__global__ __launch_bounds__(1024)
void bucket_csr_kernel(const unsigned int* __restrict__ binned,
                       const int* __restrict__ gcursor,
                       int* __restrict__ offsets,
                       float* __restrict__ inv_cnt,
                       int* __restrict__ col) {
    __shared__ int hist[256];
    __shared__ int cur[256];
    __shared__ int smB[512];
    __shared__ int wsum[8];
    __shared__ int dsum[4];
    int b = blockIdx.x;
    int tid = threadIdx.x;
    int lane = tid & 63;
    int wv = tid >> 6;

    // bucket-base scan over NBUCK=391 counts: per-wave shfl scan + 8-wave combine
    int v = (tid < NBUCK) ? gcursor[tid] : 0;
    int s = v;
#pragma unroll
    for (int off = 1; off < 64; off <<= 1) {
        int u = __shfl_up(s, off);
        if (lane >= off) s += u;
    }
    if (lane == 63 && wv < 8) wsum[wv] = s;
    __syncthreads();
    if (tid < 8) {
        int t = wsum[tid];
#pragma unroll
        for (int off = 1; off < 8; off <<= 1) {
            int u = __shfl_up(t, off);
            if (tid >= off) t += u;
        }
        wsum[tid] = t;                         // inclusive wave sums
    }
    __syncthreads();
    if (tid < 512) smB[tid] = s + (wv > 0 ? wsum[wv - 1] : 0);   // inclusive scan
    __syncthreads();
    int bucket_base = (b == 0) ? 0 : smB[b - 1];
    if (b == 0 && tid == 0) offsets[NN] = EE;

    int cnt = gcursor[b];
    const unsigned int* ePtr = binned + (size_t)b * BCAP;
    if (tid < 256) hist[tid] = 0;
    __syncthreads();
    for (int j = tid; j < cnt; j += 1024)          // ~4 iterations
        atomicAdd(&hist[ePtr[j] >> 20], 1);
    __syncthreads();
    // degree scan over 256: per-wave shfl scan + 4-wave combine
    int d = (tid < 256) ? hist[tid] : 0;
    int sc = d;
#pragma unroll
    for (int off = 1; off < 64; off <<= 1) {
        int u = __shfl_up(sc, off);
        if (lane >= off) sc += u;
    }
    if (lane == 63 && wv < 4) dsum[wv] = sc;
    __syncthreads();
    if (tid < 4) {
        int t = dsum[tid];
#pragma unroll
        for (int off = 1; off < 4; off <<= 1) {
            int u = __shfl_up(t, off);
            if (tid >= off) t += u;
        }
        dsum[tid] = t;
    }
    __syncthreads();
    if (tid < 256) {
        int incl = sc + (wv > 0 ? dsum[wv - 1] : 0);
        int node = (b << BSH) + tid;
        int pos = bucket_base + incl - d;          // exclusive prefix
        if (node < NN) {
            offsets[node] = pos;
            inv_cnt[node] = 1.0f / (1.0f + (float)d);
            cur[tid] = pos;
        }
    }
    __syncthreads();
    // place: all writes land in this bucket's contiguous col window (~16 KB, L2-resident)
    for (int j = tid; j < cnt; j += 1024) {        // ~4 iterations
        unsigned int v2 = ePtr[j];
        int pos = atomicAdd(&cur[v2 >> 20], 1);
        col[pos] = (int)(v2 & 0xFFFFF);
    }
}

// ---------- shared gather+conv body (one wave per node): returns r0,r1 for t=2*lane,2*lane+1 ----------
__device__ __forceinline__ void gather_conv_node(
    const f16x8* __restrict__ xin, const int* __restrict__ offsets,
    const int* __restrict__ col, const float* __restrict__ inv_cnt,
    f16* sbw, const float* wr, float bb, int node, int lane, int q, int p,
    float& r0, float& r1)
{
    // zero conv halos of OWN wave's row: dwords 0..3 and 68..71 (disjoint from sums 4..67)
    if (lane < 8) {
        int k = lane;
        ((int*)sbw)[(k < 4) ? k : (64 + k)] = 0;
    }

    int lo = offsets[node], hi = offsets[node + 1];
    int cnt = hi - lo;
    int my_col = (lane < cnt) ? col[lo + lane] : ZROW;   // pad lanes -> zero row
    int jn = cnt < 64 ? cnt : 64;

    const f16 z = (f16)0;
    f16x8 acc0 = {z, z, z, z, z, z, z, z};
    f16x8 acc1 = {z, z, z, z, z, z, z, z};
    if (q == 0) acc0 = xin[(node << 4) | p];       // self-loop row (f16 accumulate)

    for (int j = 0; j < jn; j += 32) {             // 32 edges: 8 indep loads in flight
        int c0 = __shfl(my_col, j + q);
        int c1 = __shfl(my_col, j + 4 + q);
        int c2 = __shfl(my_col, j + 8 + q);
        int c3 = __shfl(my_col, j + 12 + q);
        int c4 = __shfl(my_col, j + 16 + q);
        int c5 = __shfl(my_col, j + 20 + q);
        int c6 = __shfl(my_col, j + 24 + q);
        int c7 = __shfl(my_col, j + 28 + q);
        f16x8 u0 = xin[(c0 << 4) | p];
        f16x8 u1 = xin[(c1 << 4) | p];
        f16x8 u2 = xin[(c2 << 4) | p];
        f16x8 u3 = xin[(c3 << 4) | p];
        f16x8 u4 = xin[(c4 << 4) | p];
        f16x8 u5 = xin[(c5 << 4) | p];
        f16x8 u6 = xin[(c6 << 4) | p];
        f16x8 u7 = xin[(c7 << 4) | p];
        acc0 += u0; acc1 += u1;
        acc0 += u2; acc1 += u3;
        acc0 += u4; acc1 += u5;
        acc0 += u6; acc1 += u7;
    }
    for (int k = 64; k < cnt; k++) {           // degree > 64 (effectively never)
        int c = col[lo + k];
        f16x8 v = xin[(c << 4) | p];
        if (q == 0) acc0 += v;
    }
    acc0 += acc1;

    {   // combine the 4 quarter-groups: xor-16 then xor-32
        HU8 u; u.h = acc0;
        int4 o;
        o.x = __shfl_xor(u.i.x, 16); o.y = __shfl_xor(u.i.y, 16);
        o.z = __shfl_xor(u.i.z, 16); o.w = __shfl_xor(u.i.w, 16);
        HU8 w2; w2.i = o;
        acc0 += w2.h;
        u.h = acc0;
        o.x = __shfl_xor(u.i.x, 32); o.y = __shfl_xor(u.i.y, 32);
        o.z = __shfl_xor(u.i.z, 32); o.w = __shfl_xor(u.i.w, 32);
        w2.i = o;
        acc0 += w2.h;
    }

    if (q == 0) *(f16x8*)&sbw[8 + p * 8] = acc0;   // 16B-aligned, wave-private row

    // ---- epilogue (same wave, no barrier): 128 t over 64 lanes (2 t's each) ----
    int t0 = lane * 2;
    float A[10];
    const f16x2* sp = (const f16x2*)&sbw[4 + t0];  // 4B-aligned, stride-1 dwords
#pragma unroll
    for (int i = 0; i < 5; i++) {
        f16x2 v = sp[i];
        A[2 * i]     = (float)v.x;
        A[2 * i + 1] = (float)v.y;
    }
    float ic = inv_cnt[node];
    r0 = 0.0f; r1 = 0.0f;
#pragma unroll
    for (int k = 0; k < KK; k++) {
        r0 += wr[k] * A[k];
        r1 += wr[k] * A[k + 1];
    }
    r0 = fmaxf(r0 * ic + bb, 0.0f);
    r1 = fmaxf(r1 * ic + bb, 0.0f);
}

// ---------- layers 1-2: store y as f16x2 ----------
__global__ __launch_bounds__(128)
void fused_layer_kernel(const f16x8* __restrict__ xin,
                        const int* __restrict__ offsets,
                        const int* __restrict__ col,
                        const float* __restrict__ inv_cnt,
                        const float* __restrict__ w9,
                        const float* __restrict__ bptr,
                        f16x8* __restrict__ yout) {
    __shared__ __align__(16) f16 sb[2][144];
    int tid = threadIdx.x;
    int lane = tid & 63;
    int q = lane >> 4;
    int p = lane & 15;
    int w = tid >> 6;
    int node = __builtin_amdgcn_readfirstlane(blockIdx.x * 2 + w);
    float wr[KK];
#pragma unroll
    for (int k = 0; k < KK; k++) wr[k] = w9[k];
    float r0, r1;
    gather_conv_node(xin, offsets, col, inv_cnt, sb[w], wr, bptr[0],
                     node, lane, q, p, r0, r1);
    f16x2 o;
    o.x = (f16)r0;
    o.y = (f16)r1;
    ((f16x2*)yout)[node * 64 + lane] = o;            // coalesced 4B stores, 256B/wave
}

// ---------- layer 3 + fused output head ----------
// y3 is only consumed by out[t,c] = b[c] + sum_flat y3flat[t*NN+n]*Wout[c*NN+n]
// (flat reinterpret view). Each wave holds its node's 128 flat values (fp32,
// pre-quantization) at flat = node*128 + 2*lane {+1}; these span <=2 out-rows
// (tlo, tlo+1). Dot against L2-resident Wout, wave-reduce 6 floats, store one
// float4[2] partial per node. No y3 write, no atomics (R9: direct atomics = 805us).
__global__ __launch_bounds__(128)
void fused_layer_head_kernel(const f16x8* __restrict__ xin,
                             const int* __restrict__ offsets,
                             const int* __restrict__ col,
                             const float* __restrict__ inv_cnt,
                             const float* __restrict__ w9,
                             const float* __restrict__ bptr,
                             const float* __restrict__ Wout,
                             float4* __restrict__ partial) {
    __shared__ __align__(16) f16 sb[2][144];
    int tid = threadIdx.x;
    int lane = tid & 63;
    int q = lane >> 4;
    int p = lane & 15;
    int w = tid >> 6;
    int node = __builtin_amdgcn_readfirstlane(blockIdx.x * 2 + w);
    float wr[KK];
#pragma unroll
    for (int k = 0; k < KK; k++) wr[k] = w9[k];
    float r0, r1;
    gather_conv_node(xin, offsets, col, inv_cnt, sb[w], wr, bptr[0],
                     node, lane, q, p, r0, r1);

    // head: flat0 = node*128 + 2*lane; t = flat/NN in {tlo, tlo+1}; n = flat%NN
    int tlo  = __builtin_amdgcn_readfirstlane((node * 128) / NN);
    int base = node * 128 - tlo * NN;          // scalar, in [0, NN)
    int n0p = base + 2 * lane;                 // in [0, NN+127]
    int n1p = n0p + 1;
    int hi0 = n0p >= NN;
    int hi1 = n1p >= NN;
    int n0 = hi0 ? n0p - NN : n0p;
    int n1 = hi1 ? n1p - NN : n1p;
    float aA0 = 0.f, aA1 = 0.f, aA2 = 0.f;     // contributions to row tlo
    float aB0 = 0.f, aB1 = 0.f, aB2 = 0.f;     // contributions to row tlo+1
    {
        float c00 = r0 * Wout[0 * NN + n0], c10 = r0 * Wout[1 * NN + n0],
              c20 = r0 * Wout[2 * NN + n0];
        float c01 = r1 * Wout[0 * NN + n1], c11 = r1 * Wout[1 * NN + n1],
              c21 = r1 * Wout[2 * NN + n1];
        if (hi0) { aB0 += c00; aB1 += c10; aB2 += c20; }
        else     { aA0 += c00; aA1 += c10; aA2 += c20; }
        if (hi1) { aB0 += c01; aB1 += c11; aB2 += c21; }
        else     { aA0 += c01; aA1 += c11; aA2 += c21; }
    }
#pragma unroll
    for (int o = 32; o > 0; o >>= 1) {
        aA0 += __shfl_down(aA0, o); aA1 += __shfl_down(aA1, o); aA2 += __shfl_down(aA2, o);
        aB0 += __shfl_down(aB0, o); aB1 += __shfl_down(aB1, o); aB2 += __shfl_down(aB2, o);
    }
    if (lane == 0) {
        partial[2 * node]     = make_float4(aA0, aA1, aA2, 0.0f);
        partial[2 * node + 1] = make_float4(aB0, aB1, aB2, 0.0f);
    }
}

// ---------- reduce partials -> out[t,c] (128 blocks, one per t; no atomics) ----------
__global__ __launch_bounds__(256)
void reduce_out_kernel(const float4* __restrict__ partial,
                       const float* __restrict__ bout,
                       float* __restrict__ out) {
    int t = blockIdx.x;
    int tid = threadIdx.x;
    // nodes with tlo(n) in {t-1, t}:  n*128 >= (t-1)*NN  and  n*128 < (t+1)*NN
    int nlo = (t == 0) ? 0 : (((t - 1) * NN) + 127) >> 7;
    int nhi = (((t + 1) * NN) - 1) >> 7;
    if (nhi > NN - 1) nhi = NN - 1;
    float a0 = 0.f, a1 = 0.f, a2 = 0.f;
    for (int n = nlo + tid; n <= nhi; n += 256) {
        int tl = (n << 7) / NN;
        if (tl == t) {
            float4 pa = partial[2 * n];
            a0 += pa.x; a1 += pa.y; a2 += pa.z;
        } else if (tl == t - 1) {
            float4 pb = partial[2 * n + 1];
            a0 += pb.x; a1 += pb.y; a2 += pb.z;
        }
    }
#pragma unroll
    for (int o = 32; o > 0; o >>= 1) {
        a0 += __shfl_down(a0, o);
        a1 += __shfl_down(a1, o);
        a2 += __shfl_down(a2, o);
    }
    __shared__ float red[4][3];
    int wv = tid >> 6;
    if ((tid & 63) == 0) { red[wv][0] = a0; red[wv][1] = a1; red[wv][2] = a2; }
    __syncthreads();
    if (tid < 3) {
        out[t * 3 + tid] = red[0][tid] + red[1][tid] + red[2][tid] + red[3][tid]
                         + bout[tid];
    }
}

extern "C" void kernel_launch(void* const* d_in, const int* in_sizes, int n_in,
                              void* d_out, int out_size, void* d_ws, size_t ws_size,
                              hipStream_t stream) {
    const float4* x    = (const float4*)d_in[0];  // [N,T]
    const int*    ei   = (const int*)d_in[1];     // [2,E]
    const float*  cw   = (const float*)d_in[2];   // [L,1,1,K]
    const float*  cb   = (const float*)d_in[3];   // [L,1]
    const float*  Wout = (const float*)d_in[4];   // [3,N]
    const float*  bout = (const float*)d_in[5];   // [3]
    float* out = (float*)d_out;                   // [T,3]

    char* ws = (char*)d_ws;
    size_t off = 0;
    auto alloc = [&](size_t bytes) -> void* {
        void* p = ws + off;
        off += (bytes + 255) & ~(size_t)255;
        return p;
    };
    // NN+1 rows: row NN is the shared all-zero row for padded gather lanes
    f16x8*        x16     = (f16x8*)alloc((size_t)(NN + 1) * TT * 2);
    f16x8*        yA      = (f16x8*)alloc((size_t)(NN + 1) * TT * 2);
    f16x8*        yB      = (f16x8*)alloc((size_t)(NN + 1) * TT * 2);
    unsigned int* binned  = (unsigned int*)alloc((size_t)NBUCK * BCAP * 4);
    int*          gcursor = (int*)alloc((size_t)NBUCK * 4);
    int*          offsets = (int*)alloc((size_t)(NN + 1) * 4);
    float*        inv_cnt = (float*)alloc((size_t)NN * 4);
    int*          col     = (int*)alloc((size_t)EE * 4);
    float4*       partial = (float4*)alloc((size_t)NN * 2 * 16);

    // CSR build + cvt + zero-row init (ws/out are re-poisoned before every call)
    (void)hipMemsetAsync(gcursor, 0, (size_t)NBUCK * 4, stream);
    bin_cvt_kernel<<<BINB + CVTB + 1, 1024, 0, stream>>>(
        ei, gcursor, binned, x, (f16x4*)x16,
        (int*)(x16 + (size_t)NN * 16), (int*)(yA + (size_t)NN * 16),
        (int*)(yB + (size_t)NN * 16));
    bucket_csr_kernel<<<NBUCK, 1024, 0, stream>>>(binned, gcursor, offsets, inv_cnt, col);

    // layers 1-2 (conv commuted past gather; bias/mean folded exactly)
    fused_layer_kernel<<<NN / 2, 128, 0, stream>>>(x16, offsets, col, inv_cnt,
                                                   cw + 0 * KK, cb + 0, yA);
    fused_layer_kernel<<<NN / 2, 128, 0, stream>>>(yA, offsets, col, inv_cnt,
                                                   cw + 1 * KK, cb + 1, yB);
    // layer 3 with fused output head -> per-node partials (no y3 materialization)
    fused_layer_head_kernel<<<NN / 2, 128, 0, stream>>>(yB, offsets, col, inv_cnt,
                                                        cw + 2 * KK, cb + 2, Wout,
                                                        partial);
    // final reduction: 128 blocks, one per output row
    reduce_out_kernel<<<TT, 256, 0, stream>>>(partial, bout, out);
}

// Round 12
// 315.860 us; speedup vs baseline: 1.0400x; 1.0400x over previous
//
#include <hip/hip_runtime.h>

// Problem constants (match reference)
#define NN 100000
#define TT 128
#define EE 1600000
#define KK 9
#define ZROW NN                   // dedicated all-zero row for padded gather lanes

// Binned CSR build: 512-node buckets
#define BSH 9
#define BMASK 511
#define NBUCK 196                 // ceil(100000/512)
#define BCAP 10240                // avg 8163/bucket, sigma~90 -> 23 sigma headroom
#define EPB 4096                  // edges per bin block
#define BINB 391                  // ceil(EE/EPB)
#define CVTB 3125                 // NN*TT/4 / 1024

typedef _Float16 f16;
typedef __attribute__((ext_vector_type(2))) _Float16 f16x2;
typedef __attribute__((ext_vector_type(4))) _Float16 f16x4;
typedef __attribute__((ext_vector_type(8))) _Float16 f16x8;

union HU8 { f16x8 h; int4 i; };

// ---------- fused: bin edges (blocks 0..BINB) + x fp32->fp16 + zero-row init ----------
// Packed edge: (dlocal << 20) | src   (src < 2^17, dlocal < 2^9)
__global__ __launch_bounds__(1024)
void bin_cvt_kernel(const int* __restrict__ ei, int* __restrict__ gcursor,
                    unsigned int* __restrict__ binned,
                    const float4* __restrict__ x, f16x4* __restrict__ x16,
                    int* __restrict__ zx, int* __restrict__ zyA, int* __restrict__ zyB) {
    __shared__ int hist[NBUCK];
    __shared__ int gbase[NBUCK];
    int tid = threadIdx.x;

    if (blockIdx.x >= BINB + CVTB) {          // one block: zero-rows of x16/yA/yB
        int k = tid;                          // 64 dwords each
        if (k >= 0 && k < 64)         zx[k]        = 0;
        else if (k >= 64 && k < 128)  zyA[k - 64]  = 0;
        else if (k >= 128 && k < 192) zyB[k - 128] = 0;
        return;
    }
    if (blockIdx.x >= BINB) {
        // cvt part: one float4 per thread over N*T/4 (exactly CVTB*1024 elements)
        int i = (blockIdx.x - BINB) * 1024 + tid;
        float4 v = x[i];
        f16x4 o;
        o.x = (f16)v.x; o.y = (f16)v.y; o.z = (f16)v.z; o.w = (f16)v.w;
        x16[i] = o;
        return;
    }

    if (tid < NBUCK) hist[tid] = 0;
    __syncthreads();
    int base = blockIdx.x * EPB;
    unsigned int val[4];
    short bkt[4];
    short rank[4];
#pragma unroll
    for (int k = 0; k < 4; k++) {
        int e = base + k * 1024 + tid;
        bkt[k] = -1;
        if (e < EE) {
            int s = ei[e];            // src
            int d = ei[EE + e];       // dst
            bkt[k] = (short)(d >> BSH);
            val[k] = ((unsigned int)(d & BMASK) << 20) | (unsigned int)s;
            rank[k] = (short)atomicAdd(&hist[bkt[k]], 1);
        }
    }
    __syncthreads();
    if (tid < NBUCK) gbase[tid] = hist[tid] ? atomicAdd(&gcursor[tid], hist[tid]) : 0;
    __syncthreads();
#pragma unroll
    for (int k = 0; k < 4; k++) {
        if (bkt[k] >= 0)
            binned[(size_t)bkt[k] * BCAP + gbase[bkt[k]] + (int)rank[k]] = val[k];
    }
}

// ---------- per-bucket (512 nodes): bucket-base scan + hist + scan + offsets/inv_cnt + place ----------
__global__ __launch_bounds__(1024)
void bucket_csr_kernel(const unsigned int* __restrict__ binned,
                       const int* __restrict__ gcursor,
                       int* __restrict__ offsets,
                       float* __restrict__ inv_cnt,
                       int* __restrict__ col) {
    __shared__ int hist[512];
    __shared__ int cur[512];
    __shared__ int smB[256];
    __shared__ int sc[512];
    int b = blockIdx.x;
    int tid = threadIdx.x;

    // bucket-base scan over all 196 bucket counts (threads 0..255; ~µs)
    if (tid < 256) smB[tid] = (tid < NBUCK) ? gcursor[tid] : 0;
    __syncthreads();
    for (int off = 1; off < 256; off <<= 1) {
        int v = 0;
        if (tid < 256 && tid >= off) v = smB[tid - off];
        __syncthreads();
        if (tid < 256) smB[tid] += v;
        __syncthreads();
    }
    int bucket_base = (b == 0) ? 0 : smB[b - 1];
    if (b == 0 && tid == 0) offsets[NN] = EE;

    int cnt = gcursor[b];
    const unsigned int* ePtr = binned + (size_t)b * BCAP;
    if (tid < 512) hist[tid] = 0;
    __syncthreads();
    for (int j = tid; j < cnt; j += 1024)          // ~8 iterations
        atomicAdd(&hist[ePtr[j] >> 20], 1);
    __syncthreads();
    int d = (tid < 512) ? hist[tid] : 0;
    if (tid < 512) sc[tid] = d;
    __syncthreads();
    for (int off = 1; off < 512; off <<= 1) {      // inclusive scan of 512 degrees
        int v = 0;
        if (tid < 512 && tid >= off) v = sc[tid - off];
        __syncthreads();
        if (tid < 512) sc[tid] += v;
        __syncthreads();
    }
    if (tid < 512) {
        int node = (b << BSH) + tid;
        int pos = bucket_base + sc[tid] - d;       // exclusive prefix
        if (node < NN) {
            offsets[node] = pos;
            inv_cnt[node] = 1.0f / (1.0f + (float)d);
            cur[tid] = pos;
        }
    }
    __syncthreads();
    // place: all writes land in this bucket's contiguous col window (~32 KB, L2-resident)
    for (int j = tid; j < cnt; j += 1024) {        // ~8 iterations
        unsigned int v = ePtr[j];
        int pos = atomicAdd(&cur[v >> 20], 1);
        col[pos] = (int)(v & 0xFFFFF);
    }
}

// ---------- shared gather+conv body (one wave per node): returns r0,r1 for t=2*lane,2*lane+1 ----------
__device__ __forceinline__ void gather_conv_node(
    const f16x8* __restrict__ xin, const int* __restrict__ offsets,
    const int* __restrict__ col, const float* __restrict__ inv_cnt,
    f16* sbw, const float* wr, float bb, int node, int lane, int q, int p,
    float& r0, float& r1)
{
    // zero conv halos of OWN wave's row: dwords 0..3 and 68..71 (disjoint from sums 4..67)
    if (lane < 8) {
        int k = lane;
        ((int*)sbw)[(k < 4) ? k : (64 + k)] = 0;
    }

    int lo = offsets[node], hi = offsets[node + 1];
    int cnt = hi - lo;
    int my_col = (lane < cnt) ? col[lo + lane] : ZROW;   // pad lanes -> zero row
    int jn = cnt < 64 ? cnt : 64;

    const f16 z = (f16)0;
    f16x8 acc0 = {z, z, z, z, z, z, z, z};
    f16x8 acc1 = {z, z, z, z, z, z, z, z};
    if (q == 0) acc0 = xin[(node << 4) | p];       // self-loop row (f16 accumulate)

    for (int j = 0; j < jn; j += 32) {             // 32 edges: 8 indep loads in flight
        int c0 = __shfl(my_col, j + q);
        int c1 = __shfl(my_col, j + 4 + q);
        int c2 = __shfl(my_col, j + 8 + q);
        int c3 = __shfl(my_col, j + 12 + q);
        int c4 = __shfl(my_col, j + 16 + q);
        int c5 = __shfl(my_col, j + 20 + q);
        int c6 = __shfl(my_col, j + 24 + q);
        int c7 = __shfl(my_col, j + 28 + q);
        f16x8 u0 = xin[(c0 << 4) | p];
        f16x8 u1 = xin[(c1 << 4) | p];
        f16x8 u2 = xin[(c2 << 4) | p];
        f16x8 u3 = xin[(c3 << 4) | p];
        f16x8 u4 = xin[(c4 << 4) | p];
        f16x8 u5 = xin[(c5 << 4) | p];
        f16x8 u6 = xin[(c6 << 4) | p];
        f16x8 u7 = xin[(c7 << 4) | p];
        acc0 += u0; acc1 += u1;
        acc0 += u2; acc1 += u3;
        acc0 += u4; acc1 += u5;
        acc0 += u6; acc1 += u7;
    }
    for (int k = 64; k < cnt; k++) {           // degree > 64 (effectively never)
        int c = col[lo + k];
        f16x8 v = xin[(c << 4) | p];
        if (q == 0) acc0 += v;
    }
    acc0 += acc1;

    {   // combine the 4 quarter-groups: xor-16 then xor-32
        HU8 u; u.h = acc0;
        int4 o;
        o.x = __shfl_xor(u.i.x, 16); o.y = __shfl_xor(u.i.y, 16);
        o.z = __shfl_xor(u.i.z, 16); o.w = __shfl_xor(u.i.w, 16);
        HU8 w2; w2.i = o;
        acc0 += w2.h;
        u.h = acc0;
        o.x = __shfl_xor(u.i.x, 32); o.y = __shfl_xor(u.i.y, 32);
        o.z = __shfl_xor(u.i.z, 32); o.w = __shfl_xor(u.i.w, 32);
        w2.i = o;
        acc0 += w2.h;
    }

    if (q == 0) *(f16x8*)&sbw[8 + p * 8] = acc0;   // 16B-aligned, wave-private row

    // ---- epilogue (same wave, no barrier): 128 t over 64 lanes (2 t's each) ----
    int t0 = lane * 2;
    float A[10];
    const f16x2* sp = (const f16x2*)&sbw[4 + t0];  // 4B-aligned, stride-1 dwords
#pragma unroll
    for (int i = 0; i < 5; i++) {
        f16x2 v = sp[i];
        A[2 * i]     = (float)v.x;
        A[2 * i + 1] = (float)v.y;
    }
    float ic = inv_cnt[node];
    r0 = 0.0f; r1 = 0.0f;
#pragma unroll
    for (int k = 0; k < KK; k++) {
        r0 += wr[k] * A[k];
        r1 += wr[k] * A[k + 1];
    }
    r0 = fmaxf(r0 * ic + bb, 0.0f);
    r1 = fmaxf(r1 * ic + bb, 0.0f);
}

// ---------- layers 1-2: store y as f16x2 ----------
__global__ __launch_bounds__(128)
void fused_layer_kernel(const f16x8* __restrict__ xin,
                        const int* __restrict__ offsets,
                        const int* __restrict__ col,
                        const float* __restrict__ inv_cnt,
                        const float* __restrict__ w9,
                        const float* __restrict__ bptr,
                        f16x8* __restrict__ yout) {
    __shared__ __align__(16) f16 sb[2][144];
    int tid = threadIdx.x;
    int lane = tid & 63;
    int q = lane >> 4;
    int p = lane & 15;
    int w = tid >> 6;
    int node = __builtin_amdgcn_readfirstlane(blockIdx.x * 2 + w);
    float wr[KK];
#pragma unroll
    for (int k = 0; k < KK; k++) wr[k] = w9[k];
    float r0, r1;
    gather_conv_node(xin, offsets, col, inv_cnt, sb[w], wr, bptr[0],
                     node, lane, q, p, r0, r1);
    f16x2 o;
    o.x = (f16)r0;
    o.y = (f16)r1;
    ((f16x2*)yout)[node * 64 + lane] = o;            // coalesced 4B stores, 256B/wave
}

// ---------- layer 3 + fused output head ----------
// y3 is only consumed by out[t,c] = b[c] + sum_flat y3flat[t*NN+n]*Wout[c*NN+n]
// (flat reinterpret view). Each wave holds its node's 128 flat values (fp32,
// pre-quantization) at flat = node*128 + 2*lane {+1}; these span <=2 out-rows
// (tlo, tlo+1). Dot against L2-resident Wout, wave-reduce 6 floats, store one
// float4[2] partial per node. No y3 write, no atomics (R9: direct atomics = 805us).
__global__ __launch_bounds__(128)
void fused_layer_head_kernel(const f16x8* __restrict__ xin,
                             const int* __restrict__ offsets,
                             const int* __restrict__ col,
                             const float* __restrict__ inv_cnt,
                             const float* __restrict__ w9,
                             const float* __restrict__ bptr,
                             const float* __restrict__ Wout,
                             float4* __restrict__ partial) {
    __shared__ __align__(16) f16 sb[2][144];
    int tid = threadIdx.x;
    int lane = tid & 63;
    int q = lane >> 4;
    int p = lane & 15;
    int w = tid >> 6;
    int node = __builtin_amdgcn_readfirstlane(blockIdx.x * 2 + w);
    float wr[KK];
#pragma unroll
    for (int k = 0; k < KK; k++) wr[k] = w9[k];
    float r0, r1;
    gather_conv_node(xin, offsets, col, inv_cnt, sb[w], wr, bptr[0],
                     node, lane, q, p, r0, r1);

    // head: flat0 = node*128 + 2*lane; t = flat/NN in {tlo, tlo+1}; n = flat%NN
    int tlo  = __builtin_amdgcn_readfirstlane((node * 128) / NN);
    int base = node * 128 - tlo * NN;          // scalar, in [0, NN)
    int n0p = base + 2 * lane;                 // in [0, NN+127]
    int n1p = n0p + 1;
    int hi0 = n0p >= NN;
    int hi1 = n1p >= NN;
    int n0 = hi0 ? n0p - NN : n0p;
    int n1 = hi1 ? n1p - NN : n1p;
    float aA0 = 0.f, aA1 = 0.f, aA2 = 0.f;     // contributions to row tlo
    float aB0 = 0.f, aB1 = 0.f, aB2 = 0.f;     // contributions to row tlo+1
    {
        float c00 = r0 * Wout[0 * NN + n0], c10 = r0 * Wout[1 * NN + n0],
              c20 = r0 * Wout[2 * NN + n0];
        float c01 = r1 * Wout[0 * NN + n1], c11 = r1 * Wout[1 * NN + n1],
              c21 = r1 * Wout[2 * NN + n1];
        if (hi0) { aB0 += c00; aB1 += c10; aB2 += c20; }
        else     { aA0 += c00; aA1 += c10; aA2 += c20; }
        if (hi1) { aB0 += c01; aB1 += c11; aB2 += c21; }
        else     { aA0 += c01; aA1 += c11; aA2 += c21; }
    }
#pragma unroll
    for (int o = 32; o > 0; o >>= 1) {
        aA0 += __shfl_down(aA0, o); aA1 += __shfl_down(aA1, o); aA2 += __shfl_down(aA2, o);
        aB0 += __shfl_down(aB0, o); aB1 += __shfl_down(aB1, o); aB2 += __shfl_down(aB2, o);
    }
    if (lane == 0) {
        partial[2 * node]     = make_float4(aA0, aA1, aA2, 0.0f);
        partial[2 * node + 1] = make_float4(aB0, aB1, aB2, 0.0f);
    }
}

// ---------- reduce partials -> out[t,c] (128 blocks, one per t; no atomics) ----------
__global__ __launch_bounds__(256)
void reduce_out_kernel(const float4* __restrict__ partial,
                       const float* __restrict__ bout,
                       float* __restrict__ out) {
    int t = blockIdx.x;
    int tid = threadIdx.x;
    // nodes with tlo(n) in {t-1, t}:  n*128 >= (t-1)*NN  and  n*128 < (t+1)*NN
    int nlo = (t == 0) ? 0 : (((t - 1) * NN) + 127) >> 7;
    int nhi = (((t + 1) * NN) - 1) >> 7;
    if (nhi > NN - 1) nhi = NN - 1;
    float a0 = 0.f, a1 = 0.f, a2 = 0.f;
    for (int n = nlo + tid; n <= nhi; n += 256) {
        int tl = (n << 7) / NN;
        if (tl == t) {
            float4 pa = partial[2 * n];
            a0 += pa.x; a1 += pa.y; a2 += pa.z;
        } else if (tl == t - 1) {
            float4 pb = partial[2 * n + 1];
            a0 += pb.x; a1 += pb.y; a2 += pb.z;
        }
    }
#pragma unroll
    for (int o = 32; o > 0; o >>= 1) {
        a0 += __shfl_down(a0, o);
        a1 += __shfl_down(a1, o);
        a2 += __shfl_down(a2, o);
    }
    __shared__ float red[4][3];
    int wv = tid >> 6;
    if ((tid & 63) == 0) { red[wv][0] = a0; red[wv][1] = a1; red[wv][2] = a2; }
    __syncthreads();
    if (tid < 3) {
        out[t * 3 + tid] = red[0][tid] + red[1][tid] + red[2][tid] + red[3][tid]
                         + bout[tid];
    }
}

extern "C" void kernel_launch(void* const* d_in, const int* in_sizes, int n_in,
                              void* d_out, int out_size, void* d_ws, size_t ws_size,
                              hipStream_t stream) {
    const float4* x    = (const float4*)d_in[0];  // [N,T]
    const int*    ei   = (const int*)d_in[1];     // [2,E]
    const float*  cw   = (const float*)d_in[2];   // [L,1,1,K]
    const float*  cb   = (const float*)d_in[3];   // [L,1]
    const float*  Wout = (const float*)d_in[4];   // [3,N]
    const float*  bout = (const float*)d_in[5];   // [3]
    float* out = (float*)d_out;                   // [T,3]

    char* ws = (char*)d_ws;
    size_t off = 0;
    auto alloc = [&](size_t bytes) -> void* {
        void* p = ws + off;
        off += (bytes + 255) & ~(size_t)255;
        return p;
    };
    // NN+1 rows: row NN is the shared all-zero row for padded gather lanes
    f16x8*        x16     = (f16x8*)alloc((size_t)(NN + 1) * TT * 2);
    f16x8*        yA      = (f16x8*)alloc((size_t)(NN + 1) * TT * 2);
    f16x8*        yB      = (f16x8*)alloc((size_t)(NN + 1) * TT * 2);
    unsigned int* binned  = (unsigned int*)alloc((size_t)NBUCK * BCAP * 4);
    int*          gcursor = (int*)alloc((size_t)NBUCK * 4);
    int*          offsets = (int*)alloc((size_t)(NN + 1) * 4);
    float*        inv_cnt = (float*)alloc((size_t)NN * 4);
    int*          col     = (int*)alloc((size_t)EE * 4);
    float4*       partial = (float4*)alloc((size_t)NN * 2 * 16);

    // CSR build + cvt + zero-row init (ws/out are re-poisoned before every call)
    (void)hipMemsetAsync(gcursor, 0, (size_t)NBUCK * 4, stream);
    bin_cvt_kernel<<<BINB + CVTB + 1, 1024, 0, stream>>>(
        ei, gcursor, binned, x, (f16x4*)x16,
        (int*)(x16 + (size_t)NN * 16), (int*)(yA + (size_t)NN * 16),
        (int*)(yB + (size_t)NN * 16));
    bucket_csr_kernel<<<NBUCK, 1024, 0, stream>>>(binned, gcursor, offsets, inv_cnt, col);

    // layers 1-2 (conv commuted past gather; bias/mean folded exactly)
    fused_layer_kernel<<<NN / 2, 128, 0, stream>>>(x16, offsets, col, inv_cnt,
                                                   cw + 0 * KK, cb + 0, yA);
    fused_layer_kernel<<<NN / 2, 128, 0, stream>>>(yA, offsets, col, inv_cnt,
                                                   cw + 1 * KK, cb + 1, yB);
    // layer 3 with fused output head -> per-node partials (no y3 materialization)
    fused_layer_head_kernel<<<NN / 2, 128, 0, stream>>>(yB, offsets, col, inv_cnt,
                                                        cw + 2 * KK, cb + 2, Wout,
                                                        partial);
    // final reduction: 128 blocks, one per output row
    reduce_out_kernel<<<TT, 256, 0, stream>>>(partial, bout, out);
}

// Round 13
// 314.840 us; speedup vs baseline: 1.0434x; 1.0032x over previous
//
#include <hip/hip_runtime.h>

// Problem constants (match reference)
#define NN 100000
#define TT 128
#define EE 1600000
#define KK 9
#define ZROW NN                   // dedicated all-zero row for padded gather lanes

// Binned CSR build: 512-node buckets
#define BSH 9
#define BMASK 511
#define NBUCK 196                 // ceil(100000/512)
#define BCAP 10240                // avg 8163/bucket, sigma~90 -> 23 sigma headroom
#define EPB 4096                  // edges per bin block
#define BINB 391                  // ceil(EE/EPB)
#define CVTB 3125                 // NN*TT/4 / 1024

typedef _Float16 f16;
typedef __attribute__((ext_vector_type(2))) _Float16 f16x2;
typedef __attribute__((ext_vector_type(4))) _Float16 f16x4;
typedef __attribute__((ext_vector_type(8))) _Float16 f16x8;

union HU8 { f16x8 h; int4 i; };

// ---------- bin edges (blocks 0..BINB-1) + zero-row init (block BINB) ----------
// Packed edge: (dlocal << 20) | src   (src < 2^17, dlocal < 2^9)
__global__ __launch_bounds__(1024)
void bin_kernel(const int* __restrict__ ei, int* __restrict__ gcursor,
                unsigned int* __restrict__ binned,
                int* __restrict__ zx, int* __restrict__ zyA, int* __restrict__ zyB) {
    __shared__ int hist[NBUCK];
    __shared__ int gbase[NBUCK];
    int tid = threadIdx.x;

    if (blockIdx.x >= BINB) {                 // one block: zero-rows of x16/yA/yB
        int k = tid;                          // 64 dwords each
        if (k >= 0 && k < 64)         zx[k]        = 0;
        else if (k >= 64 && k < 128)  zyA[k - 64]  = 0;
        else if (k >= 128 && k < 192) zyB[k - 128] = 0;
        return;
    }

    if (tid < NBUCK) hist[tid] = 0;
    __syncthreads();
    int base = blockIdx.x * EPB;
    unsigned int val[4];
    short bkt[4];
    short rank[4];
#pragma unroll
    for (int k = 0; k < 4; k++) {
        int e = base + k * 1024 + tid;
        bkt[k] = -1;
        if (e < EE) {
            int s = ei[e];            // src
            int d = ei[EE + e];       // dst
            bkt[k] = (short)(d >> BSH);
            val[k] = ((unsigned int)(d & BMASK) << 20) | (unsigned int)s;
            rank[k] = (short)atomicAdd(&hist[bkt[k]], 1);
        }
    }
    __syncthreads();
    if (tid < NBUCK) gbase[tid] = hist[tid] ? atomicAdd(&gcursor[tid], hist[tid]) : 0;
    __syncthreads();
#pragma unroll
    for (int k = 0; k < 4; k++) {
        if (bkt[k] >= 0)
            binned[(size_t)bkt[k] * BCAP + gbase[bkt[k]] + (int)rank[k]] = val[k];
    }
}

// ---------- csr (blocks 0..NBUCK-1) OVERLAPPED with x fp32->f16 cvt (rest) ----------
// csr needs only bin output; cvt output (x16) is first consumed by layer 1 (next
// dispatch). Co-dispatching lets cvt's 3125 streaming blocks fill the ~77% of CUs
// the 196 csr blocks leave idle: serial bin+cvt+csr -> bin + max(csr, cvt).
__global__ __launch_bounds__(1024)
void csr_cvt_kernel(const unsigned int* __restrict__ binned,
                    const int* __restrict__ gcursor,
                    int* __restrict__ offsets,
                    float* __restrict__ inv_cnt,
                    int* __restrict__ col,
                    const float4* __restrict__ x, f16x4* __restrict__ x16) {
    __shared__ int hist[512];
    __shared__ int cur[512];
    __shared__ int smB[256];
    __shared__ int sc[512];
    int tid = threadIdx.x;

    if (blockIdx.x >= NBUCK) {
        // cvt part: one float4 per thread over N*T/4 (exactly CVTB*1024 elements)
        int i = (blockIdx.x - NBUCK) * 1024 + tid;
        float4 v = x[i];
        f16x4 o;
        o.x = (f16)v.x; o.y = (f16)v.y; o.z = (f16)v.z; o.w = (f16)v.w;
        x16[i] = o;
        return;
    }
    int b = blockIdx.x;

    // bucket-base scan over all 196 bucket counts (threads 0..255; ~µs)
    if (tid < 256) smB[tid] = (tid < NBUCK) ? gcursor[tid] : 0;
    __syncthreads();
    for (int off = 1; off < 256; off <<= 1) {
        int v = 0;
        if (tid < 256 && tid >= off) v = smB[tid - off];
        __syncthreads();
        if (tid < 256) smB[tid] += v;
        __syncthreads();
    }
    int bucket_base = (b == 0) ? 0 : smB[b - 1];
    if (b == 0 && tid == 0) offsets[NN] = EE;

    int cnt = gcursor[b];
    const unsigned int* ePtr = binned + (size_t)b * BCAP;
    if (tid < 512) hist[tid] = 0;
    __syncthreads();
    for (int j = tid; j < cnt; j += 1024)          // ~8 iterations
        atomicAdd(&hist[ePtr[j] >> 20], 1);
    __syncthreads();
    int d = (tid < 512) ? hist[tid] : 0;
    if (tid < 512) sc[tid] = d;
    __syncthreads();
    for (int off = 1; off < 512; off <<= 1) {      // inclusive scan of 512 degrees
        int v = 0;
        if (tid < 512 && tid >= off) v = sc[tid - off];
        __syncthreads();
        if (tid < 512) sc[tid] += v;
        __syncthreads();
    }
    if (tid < 512) {
        int node = (b << BSH) + tid;
        int pos = bucket_base + sc[tid] - d;       // exclusive prefix
        if (node < NN) {
            offsets[node] = pos;
            inv_cnt[node] = 1.0f / (1.0f + (float)d);
            cur[tid] = pos;
        }
    }
    __syncthreads();
    // place: all writes land in this bucket's contiguous col window (~32 KB, L2-resident)
    for (int j = tid; j < cnt; j += 1024) {        // ~8 iterations
        unsigned int v = ePtr[j];
        int pos = atomicAdd(&cur[v >> 20], 1);
        col[pos] = (int)(v & 0xFFFFF);
    }
}

// ---------- shared gather+conv body (one wave per node): returns r0,r1 for t=2*lane,2*lane+1 ----------
__device__ __forceinline__ void gather_conv_node(
    const f16x8* __restrict__ xin, const int* __restrict__ offsets,
    const int* __restrict__ col, const float* __restrict__ inv_cnt,
    f16* sbw, const float* wr, float bb, int node, int lane, int q, int p,
    float& r0, float& r1)
{
    // zero conv halos of OWN wave's row: dwords 0..3 and 68..71 (disjoint from sums 4..67)
    if (lane < 8) {
        int k = lane;
        ((int*)sbw)[(k < 4) ? k : (64 + k)] = 0;
    }

    int lo = offsets[node], hi = offsets[node + 1];
    int cnt = hi - lo;
    int my_col = (lane < cnt) ? col[lo + lane] : ZROW;   // pad lanes -> zero row
    int jn = cnt < 64 ? cnt : 64;

    const f16 z = (f16)0;
    f16x8 acc0 = {z, z, z, z, z, z, z, z};
    f16x8 acc1 = {z, z, z, z, z, z, z, z};
    if (q == 0) acc0 = xin[(node << 4) | p];       // self-loop row (f16 accumulate)

    for (int j = 0; j < jn; j += 32) {             // 32 edges: 8 indep loads in flight
        int c0 = __shfl(my_col, j + q);
        int c1 = __shfl(my_col, j + 4 + q);
        int c2 = __shfl(my_col, j + 8 + q);
        int c3 = __shfl(my_col, j + 12 + q);
        int c4 = __shfl(my_col, j + 16 + q);
        int c5 = __shfl(my_col, j + 20 + q);
        int c6 = __shfl(my_col, j + 24 + q);
        int c7 = __shfl(my_col, j + 28 + q);
        f16x8 u0 = xin[(c0 << 4) | p];
        f16x8 u1 = xin[(c1 << 4) | p];
        f16x8 u2 = xin[(c2 << 4) | p];
        f16x8 u3 = xin[(c3 << 4) | p];
        f16x8 u4 = xin[(c4 << 4) | p];
        f16x8 u5 = xin[(c5 << 4) | p];
        f16x8 u6 = xin[(c6 << 4) | p];
        f16x8 u7 = xin[(c7 << 4) | p];
        acc0 += u0; acc1 += u1;
        acc0 += u2; acc1 += u3;
        acc0 += u4; acc1 += u5;
        acc0 += u6; acc1 += u7;
    }
    for (int k = 64; k < cnt; k++) {           // degree > 64 (effectively never)
        int c = col[lo + k];
        f16x8 v = xin[(c << 4) | p];
        if (q == 0) acc0 += v;
    }
    acc0 += acc1;

    {   // combine the 4 quarter-groups: xor-16 then xor-32
        HU8 u; u.h = acc0;
        int4 o;
        o.x = __shfl_xor(u.i.x, 16); o.y = __shfl_xor(u.i.y, 16);
        o.z = __shfl_xor(u.i.z, 16); o.w = __shfl_xor(u.i.w, 16);
        HU8 w2; w2.i = o;
        acc0 += w2.h;
        u.h = acc0;
        o.x = __shfl_xor(u.i.x, 32); o.y = __shfl_xor(u.i.y, 32);
        o.z = __shfl_xor(u.i.z, 32); o.w = __shfl_xor(u.i.w, 32);
        w2.i = o;
        acc0 += w2.h;
    }

    if (q == 0) *(f16x8*)&sbw[8 + p * 8] = acc0;   // 16B-aligned, wave-private row

    // ---- epilogue (same wave, no barrier): 128 t over 64 lanes (2 t's each) ----
    int t0 = lane * 2;
    float A[10];
    const f16x2* sp = (const f16x2*)&sbw[4 + t0];  // 4B-aligned, stride-1 dwords
#pragma unroll
    for (int i = 0; i < 5; i++) {
        f16x2 v = sp[i];
        A[2 * i]     = (float)v.x;
        A[2 * i + 1] = (float)v.y;
    }
    float ic = inv_cnt[node];
    r0 = 0.0f; r1 = 0.0f;
#pragma unroll
    for (int k = 0; k < KK; k++) {
        r0 += wr[k] * A[k];
        r1 += wr[k] * A[k + 1];
    }
    r0 = fmaxf(r0 * ic + bb, 0.0f);
    r1 = fmaxf(r1 * ic + bb, 0.0f);
}

// ---------- layers 1-2: store y as f16x2 ----------
__global__ __launch_bounds__(128)
void fused_layer_kernel(const f16x8* __restrict__ xin,
                        const int* __restrict__ offsets,
                        const int* __restrict__ col,
                        const float* __restrict__ inv_cnt,
                        const float* __restrict__ w9,
                        const float* __restrict__ bptr,
                        f16x8* __restrict__ yout) {
    __shared__ __align__(16) f16 sb[2][144];
    int tid = threadIdx.x;
    int lane = tid & 63;
    int q = lane >> 4;
    int p = lane & 15;
    int w = tid >> 6;
    int node = __builtin_amdgcn_readfirstlane(blockIdx.x * 2 + w);
    float wr[KK];
#pragma unroll
    for (int k = 0; k < KK; k++) wr[k] = w9[k];
    float r0, r1;
    gather_conv_node(xin, offsets, col, inv_cnt, sb[w], wr, bptr[0],
                     node, lane, q, p, r0, r1);
    f16x2 o;
    o.x = (f16)r0;
    o.y = (f16)r1;
    ((f16x2*)yout)[node * 64 + lane] = o;            // coalesced 4B stores, 256B/wave
}

// ---------- layer 3 + fused output head ----------
// y3 is only consumed by out[t,c] = b[c] + sum_flat y3flat[t*NN+n]*Wout[c*NN+n]
// (flat reinterpret view). Each wave holds its node's 128 flat values (fp32,
// pre-quantization) at flat = node*128 + 2*lane {+1}; these span <=2 out-rows
// (tlo, tlo+1). Dot against L2-resident Wout, wave-reduce 6 floats, store one
// float4[2] partial per node. No y3 write, no atomics (R9: direct atomics = 805us).
__global__ __launch_bounds__(128)
void fused_layer_head_kernel(const f16x8* __restrict__ xin,
                             const int* __restrict__ offsets,
                             const int* __restrict__ col,
                             const float* __restrict__ inv_cnt,
                             const float* __restrict__ w9,
                             const float* __restrict__ bptr,
                             const float* __restrict__ Wout,
                             float4* __restrict__ partial) {
    __shared__ __align__(16) f16 sb[2][144];
    int tid = threadIdx.x;
    int lane = tid & 63;
    int q = lane >> 4;
    int p = lane & 15;
    int w = tid >> 6;
    int node = __builtin_amdgcn_readfirstlane(blockIdx.x * 2 + w);
    float wr[KK];
#pragma unroll
    for (int k = 0; k < KK; k++) wr[k] = w9[k];
    float r0, r1;
    gather_conv_node(xin, offsets, col, inv_cnt, sb[w], wr, bptr[0],
                     node, lane, q, p, r0, r1);

    // head: flat0 = node*128 + 2*lane; t = flat/NN in {tlo, tlo+1}; n = flat%NN
    int tlo  = __builtin_amdgcn_readfirstlane((node * 128) / NN);
    int base = node * 128 - tlo * NN;          // scalar, in [0, NN)
    int n0p = base + 2 * lane;                 // in [0, NN+127]
    int n1p = n0p + 1;
    int hi0 = n0p >= NN;
    int hi1 = n1p >= NN;
    int n0 = hi0 ? n0p - NN : n0p;
    int n1 = hi1 ? n1p - NN : n1p;
    float aA0 = 0.f, aA1 = 0.f, aA2 = 0.f;     // contributions to row tlo
    float aB0 = 0.f, aB1 = 0.f, aB2 = 0.f;     // contributions to row tlo+1
    {
        float c00 = r0 * Wout[0 * NN + n0], c10 = r0 * Wout[1 * NN + n0],
              c20 = r0 * Wout[2 * NN + n0];
        float c01 = r1 * Wout[0 * NN + n1], c11 = r1 * Wout[1 * NN + n1],
              c21 = r1 * Wout[2 * NN + n1];
        if (hi0) { aB0 += c00; aB1 += c10; aB2 += c20; }
        else     { aA0 += c00; aA1 += c10; aA2 += c20; }
        if (hi1) { aB0 += c01; aB1 += c11; aB2 += c21; }
        else     { aA0 += c01; aA1 += c11; aA2 += c21; }
    }
#pragma unroll
    for (int o = 32; o > 0; o >>= 1) {
        aA0 += __shfl_down(aA0, o); aA1 += __shfl_down(aA1, o); aA2 += __shfl_down(aA2, o);
        aB0 += __shfl_down(aB0, o); aB1 += __shfl_down(aB1, o); aB2 += __shfl_down(aB2, o);
    }
    if (lane == 0) {
        partial[2 * node]     = make_float4(aA0, aA1, aA2, 0.0f);
        partial[2 * node + 1] = make_float4(aB0, aB1, aB2, 0.0f);
    }
}

// ---------- reduce partials -> out[t,c] (128 blocks, one per t; no atomics) ----------
__global__ __launch_bounds__(256)
void reduce_out_kernel(const float4* __restrict__ partial,
                       const float* __restrict__ bout,
                       float* __restrict__ out) {
    int t = blockIdx.x;
    int tid = threadIdx.x;
    // nodes with tlo(n) in {t-1, t}:  n*128 >= (t-1)*NN  and  n*128 < (t+1)*NN
    int nlo = (t == 0) ? 0 : (((t - 1) * NN) + 127) >> 7;
    int nhi = (((t + 1) * NN) - 1) >> 7;
    if (nhi > NN - 1) nhi = NN - 1;
    float a0 = 0.f, a1 = 0.f, a2 = 0.f;
    for (int n = nlo + tid; n <= nhi; n += 256) {
        int tl = (n << 7) / NN;
        if (tl == t) {
            float4 pa = partial[2 * n];
            a0 += pa.x; a1 += pa.y; a2 += pa.z;
        } else if (tl == t - 1) {
            float4 pb = partial[2 * n + 1];
            a0 += pb.x; a1 += pb.y; a2 += pb.z;
        }
    }
#pragma unroll
    for (int o = 32; o > 0; o >>= 1) {
        a0 += __shfl_down(a0, o);
        a1 += __shfl_down(a1, o);
        a2 += __shfl_down(a2, o);
    }
    __shared__ float red[4][3];
    int wv = tid >> 6;
    if ((tid & 63) == 0) { red[wv][0] = a0; red[wv][1] = a1; red[wv][2] = a2; }
    __syncthreads();
    if (tid < 3) {
        out[t * 3 + tid] = red[0][tid] + red[1][tid] + red[2][tid] + red[3][tid]
                         + bout[tid];
    }
}

extern "C" void kernel_launch(void* const* d_in, const int* in_sizes, int n_in,
                              void* d_out, int out_size, void* d_ws, size_t ws_size,
                              hipStream_t stream) {
    const float4* x    = (const float4*)d_in[0];  // [N,T]
    const int*    ei   = (const int*)d_in[1];     // [2,E]
    const float*  cw   = (const float*)d_in[2];   // [L,1,1,K]
    const float*  cb   = (const float*)d_in[3];   // [L,1]
    const float*  Wout = (const float*)d_in[4];   // [3,N]
    const float*  bout = (const float*)d_in[5];   // [3]
    float* out = (float*)d_out;                   // [T,3]

    char* ws = (char*)d_ws;
    size_t off = 0;
    auto alloc = [&](size_t bytes) -> void* {
        void* p = ws + off;
        off += (bytes + 255) & ~(size_t)255;
        return p;
    };
    // NN+1 rows: row NN is the shared all-zero row for padded gather lanes
    f16x8*        x16     = (f16x8*)alloc((size_t)(NN + 1) * TT * 2);
    f16x8*        yA      = (f16x8*)alloc((size_t)(NN + 1) * TT * 2);
    f16x8*        yB      = (f16x8*)alloc((size_t)(NN + 1) * TT * 2);
    unsigned int* binned  = (unsigned int*)alloc((size_t)NBUCK * BCAP * 4);
    int*          gcursor = (int*)alloc((size_t)NBUCK * 4);
    int*          offsets = (int*)alloc((size_t)(NN + 1) * 4);
    float*        inv_cnt = (float*)alloc((size_t)NN * 4);
    int*          col     = (int*)alloc((size_t)EE * 4);
    float4*       partial = (float4*)alloc((size_t)NN * 2 * 16);

    // bin (+ zero-row init); ws/out are re-poisoned before every call
    (void)hipMemsetAsync(gcursor, 0, (size_t)NBUCK * 4, stream);
    bin_kernel<<<BINB + 1, 1024, 0, stream>>>(
        ei, gcursor, binned,
        (int*)(x16 + (size_t)NN * 16), (int*)(yA + (size_t)NN * 16),
        (int*)(yB + (size_t)NN * 16));
    // csr overlapped with fp32->f16 cvt (independent; cvt first consumed by layer 1)
    csr_cvt_kernel<<<NBUCK + CVTB, 1024, 0, stream>>>(binned, gcursor, offsets,
                                                      inv_cnt, col, x, (f16x4*)x16);

    // layers 1-2 (conv commuted past gather; bias/mean folded exactly)
    fused_layer_kernel<<<NN / 2, 128, 0, stream>>>(x16, offsets, col, inv_cnt,
                                                   cw + 0 * KK, cb + 0, yA);
    fused_layer_kernel<<<NN / 2, 128, 0, stream>>>(yA, offsets, col, inv_cnt,
                                                   cw + 1 * KK, cb + 1, yB);
    // layer 3 with fused output head -> per-node partials (no y3 materialization)
    fused_layer_head_kernel<<<NN / 2, 128, 0, stream>>>(yB, offsets, col, inv_cnt,
                                                        cw + 2 * KK, cb + 2, Wout,
                                                        partial);
    // final reduction: 128 blocks, one per output row
    reduce_out_kernel<<<TT, 256, 0, stream>>>(partial, bout, out);
}

// Round 14
// 312.517 us; speedup vs baseline: 1.0511x; 1.0074x over previous
//
#include <hip/hip_runtime.h>

// Problem constants (match reference)
#define NN 100000
#define TT 128
#define EE 1600000
#define KK 9
#define ZROW NN                   // dedicated all-zero row for padded gather lanes

// Binned CSR build: 512-node buckets
#define BSH 9
#define BMASK 511
#define NBUCK 196                 // ceil(100000/512)
#define BCAP 10240                // avg 8163/bucket, sigma~90 -> 23 sigma headroom
#define EPB 4096                  // edges per bin block
#define BINB 391                  // ceil(EE/EPB)
#define CVTB 3125                 // NN*TT/4 / 1024

typedef _Float16 f16;
typedef __attribute__((ext_vector_type(2))) _Float16 f16x2;
typedef __attribute__((ext_vector_type(4))) _Float16 f16x4;
typedef __attribute__((ext_vector_type(8))) _Float16 f16x8;

union HU8 { f16x8 h; int4 i; };

// ---------- bin edges (blocks 0..BINB-1) + zero-row init (block BINB) ----------
// Packed edge: (dlocal << 20) | src   (src < 2^17, dlocal < 2^9)
// Two-pass LDS-staged binning: pass1 hist -> scan -> per-bucket LDS bases; pass2
// stages packed edges in LDS at scan positions; copy-out writes per-bucket
// CONTIGUOUS global runs (~84B avg) instead of 1.6M scattered 4B stores (which
// were RFO-miss-bound over the 8MB binned range > 4MB per-XCD L2).
__global__ __launch_bounds__(1024)
void bin_kernel(const int* __restrict__ ei, int* __restrict__ gcursor,
                unsigned int* __restrict__ binned,
                int* __restrict__ zx, int* __restrict__ zyA, int* __restrict__ zyB) {
    __shared__ int hist[NBUCK];
    __shared__ int lbase[NBUCK];
    __shared__ int lcur[NBUCK];
    __shared__ int gbase[NBUCK];
    __shared__ int scn[256];
    __shared__ unsigned int stage[EPB];    // 16 KB
    __shared__ short sbkt[EPB];            // 8 KB
    int tid = threadIdx.x;

    if (blockIdx.x >= BINB) {                 // one block: zero-rows of x16/yA/yB
        int k = tid;                          // 64 dwords each
        if (k >= 0 && k < 64)         zx[k]        = 0;
        else if (k >= 64 && k < 128)  zyA[k - 64]  = 0;
        else if (k >= 128 && k < 192) zyB[k - 128] = 0;
        return;
    }

    if (tid < NBUCK) hist[tid] = 0;
    __syncthreads();
    int base = blockIdx.x * EPB;
#pragma unroll
    for (int k = 0; k < 4; k++) {             // pass 1: count
        int e = base + k * 1024 + tid;
        if (e < EE) atomicAdd(&hist[ei[EE + e] >> BSH], 1);
    }
    __syncthreads();
    // inclusive scan of hist over 256 slots (one-time Hillis-Steele)
    if (tid < 256) scn[tid] = (tid < NBUCK) ? hist[tid] : 0;
    __syncthreads();
    for (int off = 1; off < 256; off <<= 1) {
        int v = 0;
        if (tid < 256 && tid >= off) v = scn[tid - off];
        __syncthreads();
        if (tid < 256) scn[tid] += v;
        __syncthreads();
    }
    if (tid < NBUCK) {
        int excl = scn[tid] - hist[tid];
        lbase[tid] = excl;
        lcur[tid]  = excl;
        gbase[tid] = hist[tid] ? atomicAdd(&gcursor[tid], hist[tid]) : 0;
    }
    __syncthreads();
#pragma unroll
    for (int k = 0; k < 4; k++) {             // pass 2: stage (ei slice L2-hot)
        int e = base + k * 1024 + tid;
        if (e < EE) {
            int s = ei[e];
            int d = ei[EE + e];
            int bkt = d >> BSH;
            int r = atomicAdd(&lcur[bkt], 1);
            stage[r] = ((unsigned int)(d & BMASK) << 20) | (unsigned int)s;
            sbkt[r]  = (short)bkt;
        }
    }
    __syncthreads();
    int total = scn[255];                     // edges in this block
    for (int j = tid; j < total; j += 1024) { // coalesced copy-out (runs per bucket)
        int bkt = sbkt[j];
        binned[(size_t)bkt * BCAP + gbase[bkt] + (j - lbase[bkt])] = stage[j];
    }
}

// ---------- csr (blocks 0..NBUCK-1) OVERLAPPED with x fp32->f16 cvt (rest) ----------
__global__ __launch_bounds__(1024)
void csr_cvt_kernel(const unsigned int* __restrict__ binned,
                    const int* __restrict__ gcursor,
                    int* __restrict__ offsets,
                    float* __restrict__ inv_cnt,
                    int* __restrict__ col,
                    const float4* __restrict__ x, f16x4* __restrict__ x16) {
    __shared__ int hist[512];
    __shared__ int cur[512];
    __shared__ int smB[256];
    __shared__ int sc[512];
    int tid = threadIdx.x;

    if (blockIdx.x >= NBUCK) {
        // cvt part: one float4 per thread over N*T/4 (exactly CVTB*1024 elements)
        int i = (blockIdx.x - NBUCK) * 1024 + tid;
        float4 v = x[i];
        f16x4 o;
        o.x = (f16)v.x; o.y = (f16)v.y; o.z = (f16)v.z; o.w = (f16)v.w;
        x16[i] = o;
        return;
    }
    int b = blockIdx.x;

    // bucket-base scan over all 196 bucket counts (threads 0..255; ~µs)
    if (tid < 256) smB[tid] = (tid < NBUCK) ? gcursor[tid] : 0;
    __syncthreads();
    for (int off = 1; off < 256; off <<= 1) {
        int v = 0;
        if (tid < 256 && tid >= off) v = smB[tid - off];
        __syncthreads();
        if (tid < 256) smB[tid] += v;
        __syncthreads();
    }
    int bucket_base = (b == 0) ? 0 : smB[b - 1];
    if (b == 0 && tid == 0) offsets[NN] = EE;

    int cnt = gcursor[b];
    const unsigned int* ePtr = binned + (size_t)b * BCAP;
    if (tid < 512) hist[tid] = 0;
    __syncthreads();
    for (int j = tid; j < cnt; j += 1024)          // ~8 iterations
        atomicAdd(&hist[ePtr[j] >> 20], 1);
    __syncthreads();
    int d = (tid < 512) ? hist[tid] : 0;
    if (tid < 512) sc[tid] = d;
    __syncthreads();
    for (int off = 1; off < 512; off <<= 1) {      // inclusive scan of 512 degrees
        int v = 0;
        if (tid < 512 && tid >= off) v = sc[tid - off];
        __syncthreads();
        if (tid < 512) sc[tid] += v;
        __syncthreads();
    }
    if (tid < 512) {
        int node = (b << BSH) + tid;
        int pos = bucket_base + sc[tid] - d;       // exclusive prefix
        if (node < NN) {
            offsets[node] = pos;
            inv_cnt[node] = 1.0f / (1.0f + (float)d);
            cur[tid] = pos;
        }
    }
    __syncthreads();
    // place: all writes land in this bucket's contiguous col window (~32 KB, L2-resident)
    for (int j = tid; j < cnt; j += 1024) {        // ~8 iterations
        unsigned int v = ePtr[j];
        int pos = atomicAdd(&cur[v >> 20], 1);
        col[pos] = (int)(v & 0xFFFFF);
    }
}

// ---------- shared gather+conv body (one wave per node): returns r0,r1 for t=2*lane,2*lane+1 ----------
__device__ __forceinline__ void gather_conv_node(
    const f16x8* __restrict__ xin, const int* __restrict__ offsets,
    const int* __restrict__ col, const float* __restrict__ inv_cnt,
    f16* sbw, const float* wr, float bb, int node, int lane, int q, int p,
    float& r0, float& r1)
{
    // zero conv halos of OWN wave's row: dwords 0..3 and 68..71 (disjoint from sums 4..67)
    if (lane < 8) {
        int k = lane;
        ((int*)sbw)[(k < 4) ? k : (64 + k)] = 0;
    }

    int lo = offsets[node], hi = offsets[node + 1];
    int cnt = hi - lo;
    int my_col = (lane < cnt) ? col[lo + lane] : ZROW;   // pad lanes -> zero row
    int jn = cnt < 64 ? cnt : 64;

    const f16 z = (f16)0;
    f16x8 acc0 = {z, z, z, z, z, z, z, z};
    f16x8 acc1 = {z, z, z, z, z, z, z, z};
    if (q == 0) acc0 = xin[(node << 4) | p];       // self-loop row (f16 accumulate)

    for (int j = 0; j < jn; j += 32) {             // 32 edges: 8 indep loads in flight
        int c0 = __shfl(my_col, j + q);
        int c1 = __shfl(my_col, j + 4 + q);
        int c2 = __shfl(my_col, j + 8 + q);
        int c3 = __shfl(my_col, j + 12 + q);
        int c4 = __shfl(my_col, j + 16 + q);
        int c5 = __shfl(my_col, j + 20 + q);
        int c6 = __shfl(my_col, j + 24 + q);
        int c7 = __shfl(my_col, j + 28 + q);
        f16x8 u0 = xin[(c0 << 4) | p];
        f16x8 u1 = xin[(c1 << 4) | p];
        f16x8 u2 = xin[(c2 << 4) | p];
        f16x8 u3 = xin[(c3 << 4) | p];
        f16x8 u4 = xin[(c4 << 4) | p];
        f16x8 u5 = xin[(c5 << 4) | p];
        f16x8 u6 = xin[(c6 << 4) | p];
        f16x8 u7 = xin[(c7 << 4) | p];
        acc0 += u0; acc1 += u1;
        acc0 += u2; acc1 += u3;
        acc0 += u4; acc1 += u5;
        acc0 += u6; acc1 += u7;
    }
    for (int k = 64; k < cnt; k++) {           // degree > 64 (effectively never)
        int c = col[lo + k];
        f16x8 v = xin[(c << 4) | p];
        if (q == 0) acc0 += v;
    }
    acc0 += acc1;

    {   // combine the 4 quarter-groups: xor-16 then xor-32
        HU8 u; u.h = acc0;
        int4 o;
        o.x = __shfl_xor(u.i.x, 16); o.y = __shfl_xor(u.i.y, 16);
        o.z = __shfl_xor(u.i.z, 16); o.w = __shfl_xor(u.i.w, 16);
        HU8 w2; w2.i = o;
        acc0 += w2.h;
        u.h = acc0;
        o.x = __shfl_xor(u.i.x, 32); o.y = __shfl_xor(u.i.y, 32);
        o.z = __shfl_xor(u.i.z, 32); o.w = __shfl_xor(u.i.w, 32);
        w2.i = o;
        acc0 += w2.h;
    }

    if (q == 0) *(f16x8*)&sbw[8 + p * 8] = acc0;   // 16B-aligned, wave-private row

    // ---- epilogue (same wave, no barrier): 128 t over 64 lanes (2 t's each) ----
    int t0 = lane * 2;
    float A[10];
    const f16x2* sp = (const f16x2*)&sbw[4 + t0];  // 4B-aligned, stride-1 dwords
#pragma unroll
    for (int i = 0; i < 5; i++) {
        f16x2 v = sp[i];
        A[2 * i]     = (float)v.x;
        A[2 * i + 1] = (float)v.y;
    }
    float ic = inv_cnt[node];
    r0 = 0.0f; r1 = 0.0f;
#pragma unroll
    for (int k = 0; k < KK; k++) {
        r0 += wr[k] * A[k];
        r1 += wr[k] * A[k + 1];
    }
    r0 = fmaxf(r0 * ic + bb, 0.0f);
    r1 = fmaxf(r1 * ic + bb, 0.0f);
}

// ---------- layers 1-2: store y as f16x2 ----------
__global__ __launch_bounds__(128)
void fused_layer_kernel(const f16x8* __restrict__ xin,
                        const int* __restrict__ offsets,
                        const int* __restrict__ col,
                        const float* __restrict__ inv_cnt,
                        const float* __restrict__ w9,
                        const float* __restrict__ bptr,
                        f16x8* __restrict__ yout) {
    __shared__ __align__(16) f16 sb[2][144];
    int tid = threadIdx.x;
    int lane = tid & 63;
    int q = lane >> 4;
    int p = lane & 15;
    int w = tid >> 6;
    int node = __builtin_amdgcn_readfirstlane(blockIdx.x * 2 + w);
    float wr[KK];
#pragma unroll
    for (int k = 0; k < KK; k++) wr[k] = w9[k];
    float r0, r1;
    gather_conv_node(xin, offsets, col, inv_cnt, sb[w], wr, bptr[0],
                     node, lane, q, p, r0, r1);
    f16x2 o;
    o.x = (f16)r0;
    o.y = (f16)r1;
    ((f16x2*)yout)[node * 64 + lane] = o;            // coalesced 4B stores, 256B/wave
}

// ---------- layer 3 + fused output head ----------
// y3 is only consumed by out[t,c] = b[c] + sum_flat y3flat[t*NN+n]*Wout[c*NN+n]
// (flat reinterpret view). Each wave holds its node's 128 flat values (fp32,
// pre-quantization) at flat = node*128 + 2*lane {+1}; these span <=2 out-rows
// (tlo, tlo+1). Dot against L2-resident Wout, wave-reduce 6 floats, store one
// float4[2] partial per node. No y3 write, no atomics (R9: direct atomics = 805us).
__global__ __launch_bounds__(128)
void fused_layer_head_kernel(const f16x8* __restrict__ xin,
                             const int* __restrict__ offsets,
                             const int* __restrict__ col,
                             const float* __restrict__ inv_cnt,
                             const float* __restrict__ w9,
                             const float* __restrict__ bptr,
                             const float* __restrict__ Wout,
                             float4* __restrict__ partial) {
    __shared__ __align__(16) f16 sb[2][144];
    int tid = threadIdx.x;
    int lane = tid & 63;
    int q = lane >> 4;
    int p = lane & 15;
    int w = tid >> 6;
    int node = __builtin_amdgcn_readfirstlane(blockIdx.x * 2 + w);
    float wr[KK];
#pragma unroll
    for (int k = 0; k < KK; k++) wr[k] = w9[k];
    float r0, r1;
    gather_conv_node(xin, offsets, col, inv_cnt, sb[w], wr, bptr[0],
                     node, lane, q, p, r0, r1);

    // head: flat0 = node*128 + 2*lane; t = flat/NN in {tlo, tlo+1}; n = flat%NN
    int tlo  = __builtin_amdgcn_readfirstlane((node * 128) / NN);
    int base = node * 128 - tlo * NN;          // scalar, in [0, NN)
    int n0p = base + 2 * lane;                 // in [0, NN+127]
    int n1p = n0p + 1;
    int hi0 = n0p >= NN;
    int hi1 = n1p >= NN;
    int n0 = hi0 ? n0p - NN : n0p;
    int n1 = hi1 ? n1p - NN : n1p;
    float aA0 = 0.f, aA1 = 0.f, aA2 = 0.f;     // contributions to row tlo
    float aB0 = 0.f, aB1 = 0.f, aB2 = 0.f;     // contributions to row tlo+1
    {
        float c00 = r0 * Wout[0 * NN + n0], c10 = r0 * Wout[1 * NN + n0],
              c20 = r0 * Wout[2 * NN + n0];
        float c01 = r1 * Wout[0 * NN + n1], c11 = r1 * Wout[1 * NN + n1],
              c21 = r1 * Wout[2 * NN + n1];
        if (hi0) { aB0 += c00; aB1 += c10; aB2 += c20; }
        else     { aA0 += c00; aA1 += c10; aA2 += c20; }
        if (hi1) { aB0 += c01; aB1 += c11; aB2 += c21; }
        else     { aA0 += c01; aA1 += c11; aA2 += c21; }
    }
#pragma unroll
    for (int o = 32; o > 0; o >>= 1) {
        aA0 += __shfl_down(aA0, o); aA1 += __shfl_down(aA1, o); aA2 += __shfl_down(aA2, o);
        aB0 += __shfl_down(aB0, o); aB1 += __shfl_down(aB1, o); aB2 += __shfl_down(aB2, o);
    }
    if (lane == 0) {
        partial[2 * node]     = make_float4(aA0, aA1, aA2, 0.0f);
        partial[2 * node + 1] = make_float4(aB0, aB1, aB2, 0.0f);
    }
}

// ---------- reduce partials -> out[t,c] (128 blocks, one per t; no atomics) ----------
__global__ __launch_bounds__(256)
void reduce_out_kernel(const float4* __restrict__ partial,
                       const float* __restrict__ bout,
                       float* __restrict__ out) {
    int t = blockIdx.x;
    int tid = threadIdx.x;
    // nodes with tlo(n) in {t-1, t}:  n*128 >= (t-1)*NN  and  n*128 < (t+1)*NN
    int nlo = (t == 0) ? 0 : (((t - 1) * NN) + 127) >> 7;
    int nhi = (((t + 1) * NN) - 1) >> 7;
    if (nhi > NN - 1) nhi = NN - 1;
    float a0 = 0.f, a1 = 0.f, a2 = 0.f;
    for (int n = nlo + tid; n <= nhi; n += 256) {
        int tl = (n << 7) / NN;
        if (tl == t) {
            float4 pa = partial[2 * n];
            a0 += pa.x; a1 += pa.y; a2 += pa.z;
        } else if (tl == t - 1) {
            float4 pb = partial[2 * n + 1];
            a0 += pb.x; a1 += pb.y; a2 += pb.z;
        }
    }
#pragma unroll
    for (int o = 32; o > 0; o >>= 1) {
        a0 += __shfl_down(a0, o);
        a1 += __shfl_down(a1, o);
        a2 += __shfl_down(a2, o);
    }
    __shared__ float red[4][3];
    int wv = tid >> 6;
    if ((tid & 63) == 0) { red[wv][0] = a0; red[wv][1] = a1; red[wv][2] = a2; }
    __syncthreads();
    if (tid < 3) {
        out[t * 3 + tid] = red[0][tid] + red[1][tid] + red[2][tid] + red[3][tid]
                         + bout[tid];
    }
}

extern "C" void kernel_launch(void* const* d_in, const int* in_sizes, int n_in,
                              void* d_out, int out_size, void* d_ws, size_t ws_size,
                              hipStream_t stream) {
    const float4* x    = (const float4*)d_in[0];  // [N,T]
    const int*    ei   = (const int*)d_in[1];     // [2,E]
    const float*  cw   = (const float*)d_in[2];   // [L,1,1,K]
    const float*  cb   = (const float*)d_in[3];   // [L,1]
    const float*  Wout = (const float*)d_in[4];   // [3,N]
    const float*  bout = (const float*)d_in[5];   // [3]
    float* out = (float*)d_out;                   // [T,3]

    char* ws = (char*)d_ws;
    size_t off = 0;
    auto alloc = [&](size_t bytes) -> void* {
        void* p = ws + off;
        off += (bytes + 255) & ~(size_t)255;
        return p;
    };
    // NN+1 rows: row NN is the shared all-zero row for padded gather lanes
    f16x8*        x16     = (f16x8*)alloc((size_t)(NN + 1) * TT * 2);
    f16x8*        yA      = (f16x8*)alloc((size_t)(NN + 1) * TT * 2);
    f16x8*        yB      = (f16x8*)alloc((size_t)(NN + 1) * TT * 2);
    unsigned int* binned  = (unsigned int*)alloc((size_t)NBUCK * BCAP * 4);
    int*          gcursor = (int*)alloc((size_t)NBUCK * 4);
    int*          offsets = (int*)alloc((size_t)(NN + 1) * 4);
    float*        inv_cnt = (float*)alloc((size_t)NN * 4);
    int*          col     = (int*)alloc((size_t)EE * 4);
    float4*       partial = (float4*)alloc((size_t)NN * 2 * 16);

    // bin (+ zero-row init); ws/out are re-poisoned before every call
    (void)hipMemsetAsync(gcursor, 0, (size_t)NBUCK * 4, stream);
    bin_kernel<<<BINB + 1, 1024, 0, stream>>>(
        ei, gcursor, binned,
        (int*)(x16 + (size_t)NN * 16), (int*)(yA + (size_t)NN * 16),
        (int*)(yB + (size_t)NN * 16));
    // csr overlapped with fp32->f16 cvt (independent; cvt first consumed by layer 1)
    csr_cvt_kernel<<<NBUCK + CVTB, 1024, 0, stream>>>(binned, gcursor, offsets,
                                                      inv_cnt, col, x, (f16x4*)x16);

    // layers 1-2 (conv commuted past gather; bias/mean folded exactly)
    fused_layer_kernel<<<NN / 2, 128, 0, stream>>>(x16, offsets, col, inv_cnt,
                                                   cw + 0 * KK, cb + 0, yA);
    fused_layer_kernel<<<NN / 2, 128, 0, stream>>>(yA, offsets, col, inv_cnt,
                                                   cw + 1 * KK, cb + 1, yB);
    // layer 3 with fused output head -> per-node partials (no y3 materialization)
    fused_layer_head_kernel<<<NN / 2, 128, 0, stream>>>(yB, offsets, col, inv_cnt,
                                                        cw + 2 * KK, cb + 2, Wout,
                                                        partial);
    // final reduction: 128 blocks, one per output row
    reduce_out_kernel<<<TT, 256, 0, stream>>>(partial, bout, out);
}